// Round 3
// baseline (547.365 us; speedup 1.0000x reference)
//
#include <hip/hip_runtime.h>
#include <hip/hip_bf16.h>
#include <cstdint>

// SimpleGAT on MI355X. Round 3: inputs fp32, OUTPUT fp32 (reference dtypes;
//   the "(bf16" in the harness label is hard-coded text, not evidence).
//   R1 NaN = fp32 inputs read as bf16. R2 0.88 = bf16 values written into an
//   fp32 output buffer. This round: identical pipeline, fp32 outputs.
//
// GEMMs: split-bf16 MFMA (a ~ ah+al): ah*bh + ah*bl + al*bh, residual ~2^-17.
// MFMA 16x16x32 bf16 layouts (guide m89/m91/m120 + CDNA ISA convention):
//   A: lane holds A[m=lane&15][k=(lane>>4)*8 + j], j=0..7
//   B: lane holds B[k=(lane>>4)*8 + j][n=lane&15]   (pre-swizzled contiguous)
//   C/D: col = lane&15, row = (lane>>4)*4 + reg

#define NNODES 20000
#define NEDGES 320000
#define ETOT   340000   // NEDGES + NNODES self loops
#define F1     512      // HEADS*HID
#define F2     256      // OUT_CH
#define HEADS  4

typedef __bf16 bf16;
typedef __attribute__((ext_vector_type(8))) __bf16 bf16x8;
typedef __attribute__((ext_vector_type(4))) float f32x4;

// ---------------- CSR build ----------------
__global__ void deg_count(const int* __restrict__ ei, int* __restrict__ deg) {
    int e = blockIdx.x * blockDim.x + threadIdx.x;
    if (e >= ETOT) return;
    int dst = (e < NEDGES) ? ei[NEDGES + e] : (e - NEDGES);
    atomicAdd(&deg[dst], 1);
}

__global__ void scan_deg(const int* __restrict__ deg, int* __restrict__ offs,
                         int* __restrict__ cur) {
    __shared__ int buf[1024];
    __shared__ int base;
    if (threadIdx.x == 0) { base = 0; offs[0] = 0; }
    __syncthreads();
    for (int start = 0; start < NNODES; start += 1024) {
        int i = start + (int)threadIdx.x;
        int v = (i < NNODES) ? deg[i] : 0;
        buf[threadIdx.x] = v;
        __syncthreads();
        for (int o = 1; o < 1024; o <<= 1) {
            int t = (threadIdx.x >= (unsigned)o) ? buf[threadIdx.x - o] : 0;
            __syncthreads();
            buf[threadIdx.x] += t;
            __syncthreads();
        }
        int incl = buf[threadIdx.x] + base;
        if (i < NNODES) { offs[i + 1] = incl; cur[i] = incl - v; }
        __syncthreads();
        if (threadIdx.x == 1023) base = incl;
        __syncthreads();
    }
}

__global__ void fill_csr(const int* __restrict__ ei, int* __restrict__ cur,
                         int* __restrict__ csr_src, int* __restrict__ csr_eid) {
    int e = blockIdx.x * blockDim.x + threadIdx.x;
    if (e >= ETOT) return;
    int src, dst;
    if (e < NEDGES) { src = ei[e]; dst = ei[NEDGES + e]; }
    else            { src = dst = e - NEDGES; }
    int p = atomicAdd(&cur[dst], 1);
    csr_src[p] = src;
    csr_eid[p] = e;
}

// ---------------- W swizzle (fp32 -> hi/lo bf16 B-fragment order) ----------------
// frag idx: ((kt*(N/16)+nt)*64 + lane)*8 + j  <-  W[(kt*32 + (lane>>4)*8 + j)*N + nt*16 + (lane&15)]
__global__ void swizzle_w(const float* __restrict__ W, bf16* __restrict__ Wh,
                          bf16* __restrict__ Wl, int K, int N) {
    int idx = blockIdx.x * blockDim.x + threadIdx.x;  // one thread per 8 elements
    int total = (K * N) >> 3;
    if (idx >= total) return;
    int lane = idx & 63;
    int tile = idx >> 6;            // kt*(N/16) + nt
    int NT = N >> 4;
    int kt = tile / NT, nt = tile - kt * NT;
    int krow = kt * 32 + (lane >> 4) * 8;
    int col  = nt * 16 + (lane & 15);
    union { bf16 b[8]; uint4 u; } hi, lo;
#pragma unroll
    for (int j = 0; j < 8; j++) {
        float w = W[(size_t)(krow + j) * N + col];
        bf16 h = (bf16)w;
        hi.b[j] = h;
        lo.b[j] = (bf16)(w - (float)h);
    }
    *(uint4*)(Wh + (size_t)idx * 8) = hi.u;
    *(uint4*)(Wl + (size_t)idx * 8) = lo.u;
}

// ---------------- split-bf16 MFMA GEMM: C[M,N] = A[M,K]*B[K,N], fp32 in/out ------
template <int K, int N>
__global__ __launch_bounds__(256) void gemm_mfma(const float* __restrict__ A,
                                                 const bf16* __restrict__ Bh,
                                                 const bf16* __restrict__ Bl,
                                                 float* __restrict__ C, int M) {
    const int lane = threadIdx.x & 63;
    const int wave = threadIdx.x >> 6;
    const int row_base = blockIdx.x * 64 + wave * 16;
    const int colt0 = blockIdx.y * 4;   // 4 col-tiles of 16
    f32x4 acc[4] = {};
    int arow = row_base + (lane & 15);
    if (arow >= M) arow = M - 1;        // clamp; stores are guarded
    const float* aptr = A + (size_t)arow * K + ((lane >> 4) * 8);
    constexpr int NT = N / 16;
#pragma unroll 2
    for (int kt = 0; kt < K / 32; ++kt) {
        float av[8];
        *(float4*)(av)     = *(const float4*)(aptr + kt * 32);
        *(float4*)(av + 4) = *(const float4*)(aptr + kt * 32 + 4);
        bf16x8 ah, al;
#pragma unroll
        for (int j = 0; j < 8; j++) {
            bf16 h = (bf16)av[j];
            ah[j] = h;
            al[j] = (bf16)(av[j] - (float)h);
        }
#pragma unroll
        for (int c = 0; c < 4; c++) {
            size_t fi = ((size_t)(kt * NT + colt0 + c) * 64 + lane) * 8;
            bf16x8 bh = *(const bf16x8*)(Bh + fi);
            bf16x8 bl = *(const bf16x8*)(Bl + fi);
            acc[c] = __builtin_amdgcn_mfma_f32_16x16x32_bf16(ah, bh, acc[c], 0, 0, 0);
            acc[c] = __builtin_amdgcn_mfma_f32_16x16x32_bf16(ah, bl, acc[c], 0, 0, 0);
            acc[c] = __builtin_amdgcn_mfma_f32_16x16x32_bf16(al, bh, acc[c], 0, 0, 0);
        }
    }
    const int crow0 = row_base + (lane >> 4) * 4;
    const int col = lane & 15;
#pragma unroll
    for (int c = 0; c < 4; c++)
#pragma unroll
        for (int r = 0; r < 4; r++) {
            int rr = crow0 + r;
            if (rr < M) C[(size_t)rr * N + (colt0 + c) * 16 + col] = acc[c][r];
        }
}

// ---------------- attention coefficients ----------------
// layer1: as1[n,h] = dot(h1[n,h,:], a_src1[h,:]) ; one wave per node, lane owns 8 ch
__global__ void attn_coef1(const float* __restrict__ h1, const float* __restrict__ asrc,
                           const float* __restrict__ adst, float* __restrict__ as1,
                           float* __restrict__ ad1) {
    int wave = threadIdx.x >> 6, lane = threadIdx.x & 63;
    int n = blockIdx.x * 4 + wave;
    if (n >= NNODES) return;
    int h = lane >> 4;                       // lanes 0-15 -> head0, etc.
    const float* hp = h1 + (size_t)n * F1 + lane * 8;
    float ss = 0.f, sd = 0.f;
#pragma unroll
    for (int j = 0; j < 8; j++) {
        float v = hp[j];
        int c = (lane & 15) * 8 + j;         // channel within head
        ss += v * asrc[h * 128 + c];
        sd += v * adst[h * 128 + c];
    }
    for (int o = 1; o < 16; o <<= 1) {       // reduce within 16-lane head group
        ss += __shfl_xor(ss, o);
        sd += __shfl_xor(sd, o);
    }
    if ((lane & 15) == 0) { as1[n * 4 + h] = ss; ad1[n * 4 + h] = sd; }
}

// layer2: 1 head, 256 ch; one wave per node, lane owns 4 ch
__global__ void attn_coef2(const float* __restrict__ h2, const float* __restrict__ asrc,
                           const float* __restrict__ adst, float* __restrict__ as2,
                           float* __restrict__ ad2) {
    int wave = threadIdx.x >> 6, lane = threadIdx.x & 63;
    int n = blockIdx.x * 4 + wave;
    if (n >= NNODES) return;
    const float* hp = h2 + (size_t)n * F2 + lane * 4;
    float ss = 0.f, sd = 0.f;
#pragma unroll
    for (int j = 0; j < 4; j++) {
        float v = hp[j];
        ss += v * asrc[lane * 4 + j];
        sd += v * adst[lane * 4 + j];
    }
    for (int o = 1; o < 64; o <<= 1) {
        ss += __shfl_xor(ss, o);
        sd += __shfl_xor(sd, o);
    }
    if (lane == 0) { as2[n] = ss; ad2[n] = sd; }
}

// ---------------- layer 1 softmax + aggregate (+bias+ELU, fp32 out) --------------
__global__ __launch_bounds__(256) void agg1(const float* __restrict__ h1,
                                            const float* __restrict__ as1,
                                            const float* __restrict__ ad1,
                                            const int* __restrict__ offs,
                                            const int* __restrict__ csr_src,
                                            const int* __restrict__ csr_eid,
                                            const float* __restrict__ b1,
                                            float* __restrict__ alpha1,
                                            float* __restrict__ h1e) {
    const int n = blockIdx.x;
    const int tid = threadIdx.x;
    const int lane = tid & 63, wave = tid >> 6;
    const int beg = offs[n];
    const int deg = offs[n + 1] - beg;

    __shared__ float wbuf[4][4];   // [wave][head]
    __shared__ float gmax[4], gden[4];

    float adn[4];
#pragma unroll
    for (int h = 0; h < 4; h++) adn[h] = ad1[n * 4 + h];

    // pass 1: per-head max of leaky(e)
    float lm[4] = {-1e30f, -1e30f, -1e30f, -1e30f};
    for (int i = tid; i < deg; i += 256) {
        int s = csr_src[beg + i];
#pragma unroll
        for (int h = 0; h < 4; h++) {
            float v = as1[s * 4 + h] + adn[h];
            v = v > 0.f ? v : 0.2f * v;
            lm[h] = fmaxf(lm[h], v);
        }
    }
#pragma unroll
    for (int h = 0; h < 4; h++)
        for (int o = 1; o < 64; o <<= 1) lm[h] = fmaxf(lm[h], __shfl_xor(lm[h], o));
    if (lane == 0)
#pragma unroll
        for (int h = 0; h < 4; h++) wbuf[wave][h] = lm[h];
    __syncthreads();
    if (tid < 4)
        gmax[tid] = fmaxf(fmaxf(wbuf[0][tid], wbuf[1][tid]), fmaxf(wbuf[2][tid], wbuf[3][tid]));
    __syncthreads();
    float mx[4];
#pragma unroll
    for (int h = 0; h < 4; h++) mx[h] = gmax[h];

    // pass 2: denom
    float ls[4] = {0.f, 0.f, 0.f, 0.f};
    for (int i = tid; i < deg; i += 256) {
        int s = csr_src[beg + i];
#pragma unroll
        for (int h = 0; h < 4; h++) {
            float v = as1[s * 4 + h] + adn[h];
            v = v > 0.f ? v : 0.2f * v;
            ls[h] += __expf(v - mx[h]);
        }
    }
#pragma unroll
    for (int h = 0; h < 4; h++)
        for (int o = 1; o < 64; o <<= 1) ls[h] += __shfl_xor(ls[h], o);
    if (lane == 0)
#pragma unroll
        for (int h = 0; h < 4; h++) wbuf[wave][h] = ls[h];
    __syncthreads();
    if (tid < 4)
        gden[tid] = wbuf[0][tid] + wbuf[1][tid] + wbuf[2][tid] + wbuf[3][tid];
    __syncthreads();
    float rden[4];
#pragma unroll
    for (int h = 0; h < 4; h++) rden[h] = 1.f / gden[h];

    // pass 3: write alpha1 (fp32 output)
    for (int i = tid; i < deg; i += 256) {
        int s = csr_src[beg + i];
        int eid = csr_eid[beg + i];
#pragma unroll
        for (int h = 0; h < 4; h++) {
            float v = as1[s * 4 + h] + adn[h];
            v = v > 0.f ? v : 0.2f * v;
            alpha1[(size_t)eid * 4 + h] = __expf(v - mx[h]) * rden[h];
        }
    }

    // pass 4: aggregate; thread owns channels tid and tid+256
    const int ch0 = tid, ch1 = tid + 256;
    const int h0 = ch0 >> 7, h1i = ch1 >> 7;
    float acc0 = 0.f, acc1 = 0.f;
    for (int i = 0; i < deg; i++) {
        int s = csr_src[beg + i];
        float v0 = as1[s * 4 + h0] + adn[h0];
        v0 = v0 > 0.f ? v0 : 0.2f * v0;
        float a0 = __expf(v0 - mx[h0]) * rden[h0];
        float v1 = as1[s * 4 + h1i] + adn[h1i];
        v1 = v1 > 0.f ? v1 : 0.2f * v1;
        float a1 = __expf(v1 - mx[h1i]) * rden[h1i];
        const float* hr = h1 + (size_t)s * F1;
        acc0 += a0 * hr[ch0];
        acc1 += a1 * hr[ch1];
    }
    float o0 = acc0 + b1[ch0];
    float o1 = acc1 + b1[ch1];
    o0 = o0 > 0.f ? o0 : expm1f(o0);   // ELU
    o1 = o1 > 0.f ? o1 : expm1f(o1);
    h1e[(size_t)n * F1 + ch0] = o0;
    h1e[(size_t)n * F1 + ch1] = o1;
}

// ---------------- layer 2 softmax + aggregate (writes final out + alpha2) --------
__global__ __launch_bounds__(256) void agg2(const float* __restrict__ h2,
                                            const float* __restrict__ as2,
                                            const float* __restrict__ ad2,
                                            const int* __restrict__ offs,
                                            const int* __restrict__ csr_src,
                                            const int* __restrict__ csr_eid,
                                            const float* __restrict__ b2,
                                            float* __restrict__ alpha2,
                                            float* __restrict__ out) {
    const int n = blockIdx.x;
    const int tid = threadIdx.x;
    const int lane = tid & 63, wave = tid >> 6;
    const int beg = offs[n];
    const int deg = offs[n + 1] - beg;

    __shared__ float wbuf[4];
    __shared__ float gm, gd;

    float adn = ad2[n];
    float lm = -1e30f;
    for (int i = tid; i < deg; i += 256) {
        int s = csr_src[beg + i];
        float v = as2[s] + adn;
        v = v > 0.f ? v : 0.2f * v;
        lm = fmaxf(lm, v);
    }
    for (int o = 1; o < 64; o <<= 1) lm = fmaxf(lm, __shfl_xor(lm, o));
    if (lane == 0) wbuf[wave] = lm;
    __syncthreads();
    if (tid == 0) gm = fmaxf(fmaxf(wbuf[0], wbuf[1]), fmaxf(wbuf[2], wbuf[3]));
    __syncthreads();
    float mx = gm;

    float ls = 0.f;
    for (int i = tid; i < deg; i += 256) {
        int s = csr_src[beg + i];
        float v = as2[s] + adn;
        v = v > 0.f ? v : 0.2f * v;
        ls += __expf(v - mx);
    }
    for (int o = 1; o < 64; o <<= 1) ls += __shfl_xor(ls, o);
    if (lane == 0) wbuf[wave] = ls;
    __syncthreads();
    if (tid == 0) gd = wbuf[0] + wbuf[1] + wbuf[2] + wbuf[3];
    __syncthreads();
    float rden = 1.f / gd;

    for (int i = tid; i < deg; i += 256) {
        int s = csr_src[beg + i];
        int eid = csr_eid[beg + i];
        float v = as2[s] + adn;
        v = v > 0.f ? v : 0.2f * v;
        alpha2[eid] = __expf(v - mx) * rden;
    }

    // aggregate: thread owns channel tid (F2 == 256)
    float acc = 0.f;
    for (int i = 0; i < deg; i++) {
        int s = csr_src[beg + i];
        float v = as2[s] + adn;
        v = v > 0.f ? v : 0.2f * v;
        float a = __expf(v - mx) * rden;
        acc += a * h2[(size_t)s * F2 + tid];
    }
    out[(size_t)n * F2 + tid] = acc + b2[tid];
}

// ---------------- launch ----------------
extern "C" void kernel_launch(void* const* d_in, const int* in_sizes, int n_in,
                              void* d_out, int out_size, void* d_ws, size_t ws_size,
                              hipStream_t stream) {
    const float* x      = (const float*)d_in[0];
    const int*   ei     = (const int*)d_in[1];
    const float* W1     = (const float*)d_in[2];
    const float* a_src1 = (const float*)d_in[3];
    const float* a_dst1 = (const float*)d_in[4];
    const float* b1     = (const float*)d_in[5];
    const float* W2     = (const float*)d_in[6];
    const float* a_src2 = (const float*)d_in[7];
    const float* a_dst2 = (const float*)d_in[8];
    const float* b2     = (const float*)d_in[9];

    char* ws = (char*)d_ws;
    size_t off = 0;
    auto alloc = [&](size_t bytes) -> char* {
        char* p = ws + off;
        off += (bytes + 255) & ~(size_t)255;
        return p;
    };
    float* h1   = (float*)alloc((size_t)NNODES * F1 * 4);   // 41.0 MB
    float* h2   = (float*)alloc((size_t)NNODES * F2 * 4);   // 20.5 MB
    float* h1e  = (float*)alloc((size_t)NNODES * F1 * 4);   // 41.0 MB
    float* as1  = (float*)alloc((size_t)NNODES * 4 * 4);
    float* ad1  = (float*)alloc((size_t)NNODES * 4 * 4);
    float* as2  = (float*)alloc((size_t)NNODES * 4);
    float* ad2  = (float*)alloc((size_t)NNODES * 4);
    bf16*  W1h  = (bf16*) alloc((size_t)512 * 512 * 2);
    bf16*  W1l  = (bf16*) alloc((size_t)512 * 512 * 2);
    bf16*  W2h  = (bf16*) alloc((size_t)512 * 256 * 2);
    bf16*  W2l  = (bf16*) alloc((size_t)512 * 256 * 2);
    int*   deg  = (int*)  alloc((size_t)NNODES * 4);
    int*   offs = (int*)  alloc((size_t)(NNODES + 1) * 4);
    int*   cur  = (int*)  alloc((size_t)NNODES * 4);
    int*   csrS = (int*)  alloc((size_t)ETOT * 4);
    int*   csrE = (int*)  alloc((size_t)ETOT * 4);

    float* out2   = (float*)d_out;                      // [20000,256]
    float* alpha1 = out2 + (size_t)NNODES * F2;         // [340000,4]
    float* alpha2 = alpha1 + (size_t)ETOT * HEADS;      // [340000]

    hipMemsetAsync(deg, 0, (size_t)NNODES * 4, stream);
    deg_count<<<(ETOT + 255) / 256, 256, 0, stream>>>(ei, deg);
    scan_deg<<<1, 1024, 0, stream>>>(deg, offs, cur);
    fill_csr<<<(ETOT + 255) / 256, 256, 0, stream>>>(ei, cur, csrS, csrE);

    swizzle_w<<<(512 * 512 / 8 + 255) / 256, 256, 0, stream>>>(W1, W1h, W1l, 512, 512);
    swizzle_w<<<(512 * 256 / 8 + 255) / 256, 256, 0, stream>>>(W2, W2h, W2l, 512, 256);

    gemm_mfma<512, 512><<<dim3(313, 8), 256, 0, stream>>>(x, W1h, W1l, h1, NNODES);
    attn_coef1<<<5000, 256, 0, stream>>>(h1, a_src1, a_dst1, as1, ad1);
    agg1<<<NNODES, 256, 0, stream>>>(h1, as1, ad1, offs, csrS, csrE, b1, alpha1, h1e);

    gemm_mfma<512, 256><<<dim3(313, 4), 256, 0, stream>>>(h1e, W2h, W2l, h2, NNODES);
    attn_coef2<<<5000, 256, 0, stream>>>(h2, a_src2, a_dst2, as2, ad2);
    agg2<<<NNODES, 256, 0, stream>>>(h2, as2, ad2, offs, csrS, csrE, b2, alpha2, out2);
}

// Round 4
// 432.301 us; speedup vs baseline: 1.2662x; 1.2662x over previous
//
#include <hip/hip_runtime.h>
#include <hip/hip_bf16.h>
#include <cstdint>

// SimpleGAT on MI355X. Round 4: perf pass.
//   R3 passed @547us; top-5 dispatches all agg1 (133us, VALUBusy 72%, Mfma 0)
//   -> agg was VALU-bound on 128x-redundant exp recompute + fp32 gathers.
// Changes:
//   1. agg1/agg2: per-edge alpha computed ONCE into LDS tiles; aggregation
//      gathers h rows in bf16 (h1b/h2b written by GEMM epilogue). 2x fewer
//      gather bytes, ~5x less VALU.
//   2. scan_deg: 20 elem/thread serial + single block scan (was ~400 barriers).
//   3. gemm: 8 col-tiles per wave (halves A refetch; grid-y 4/2).
//
// MFMA 16x16x32 bf16 layouts (verified R3):
//   A: lane holds A[m=lane&15][k=(lane>>4)*8 + j], j=0..7
//   B: lane holds B[k=(lane>>4)*8 + j][n=lane&15]   (pre-swizzled contiguous)
//   C/D: col = lane&15, row = (lane>>4)*4 + reg

#define NNODES 20000
#define NEDGES 320000
#define ETOT   340000   // NEDGES + NNODES self loops
#define F1     512      // HEADS*HID
#define F2     256      // OUT_CH
#define HEADS  4

typedef __bf16 bf16;
typedef __attribute__((ext_vector_type(8))) __bf16 bf16x8;
typedef __attribute__((ext_vector_type(4))) float f32x4;

__device__ __forceinline__ float bflo(unsigned p) { return __uint_as_float(p << 16); }
__device__ __forceinline__ float bfhi(unsigned p) { return __uint_as_float(p & 0xffff0000u); }

// ---------------- CSR build ----------------
__global__ void deg_count(const int* __restrict__ ei, int* __restrict__ deg) {
    int e = blockIdx.x * blockDim.x + threadIdx.x;
    if (e >= ETOT) return;
    int dst = (e < NEDGES) ? ei[NEDGES + e] : (e - NEDGES);
    atomicAdd(&deg[dst], 1);
}

// 1024 threads, 20 elems each (20480 >= 20000); one block-scan.
__global__ void scan_deg(const int* __restrict__ deg, int* __restrict__ offs,
                         int* __restrict__ cur) {
    __shared__ int sums[1024];
    const int t = threadIdx.x;
    const int PER = 20;
    int base = t * PER;
    int local[PER];
    int run = 0;
#pragma unroll
    for (int j = 0; j < PER; j++) {
        int i = base + j;
        int v = (i < NNODES) ? deg[i] : 0;
        local[j] = run;           // exclusive within thread
        run += v;
    }
    sums[t] = run;
    __syncthreads();
    for (int o = 1; o < 1024; o <<= 1) {
        int v = (t >= o) ? sums[t - o] : 0;
        __syncthreads();
        sums[t] += v;
        __syncthreads();
    }
    int texcl = (t == 0) ? 0 : sums[t - 1];
#pragma unroll
    for (int j = 0; j < PER; j++) {
        int i = base + j;
        if (i < NNODES) {
            int e = texcl + local[j];
            cur[i] = e;
            offs[i] = e;
        }
    }
    if (t == 1023) offs[NNODES] = sums[1023];
}

__global__ void fill_csr(const int* __restrict__ ei, int* __restrict__ cur,
                         int* __restrict__ csr_src, int* __restrict__ csr_eid) {
    int e = blockIdx.x * blockDim.x + threadIdx.x;
    if (e >= ETOT) return;
    int src, dst;
    if (e < NEDGES) { src = ei[e]; dst = ei[NEDGES + e]; }
    else            { src = dst = e - NEDGES; }
    int p = atomicAdd(&cur[dst], 1);
    csr_src[p] = src;
    csr_eid[p] = e;
}

// ---------------- W swizzle (fp32 -> hi/lo bf16 B-fragment order) ----------------
__global__ void swizzle_w(const float* __restrict__ W, bf16* __restrict__ Wh,
                          bf16* __restrict__ Wl, int K, int N) {
    int idx = blockIdx.x * blockDim.x + threadIdx.x;  // one thread per 8 elements
    int total = (K * N) >> 3;
    if (idx >= total) return;
    int lane = idx & 63;
    int tile = idx >> 6;            // kt*(N/16) + nt
    int NT = N >> 4;
    int kt = tile / NT, nt = tile - kt * NT;
    int krow = kt * 32 + (lane >> 4) * 8;
    int col  = nt * 16 + (lane & 15);
    union { bf16 b[8]; uint4 u; } hi, lo;
#pragma unroll
    for (int j = 0; j < 8; j++) {
        float w = W[(size_t)(krow + j) * N + col];
        bf16 h = (bf16)w;
        hi.b[j] = h;
        lo.b[j] = (bf16)(w - (float)h);
    }
    *(uint4*)(Wh + (size_t)idx * 8) = hi.u;
    *(uint4*)(Wl + (size_t)idx * 8) = lo.u;
}

// ------- split-bf16 MFMA GEMM: C[M,N]=A*B fp32, plus bf16 copy Cb -------
// wave covers 16 rows x 128 cols (8 col-tiles); block = 4 waves = 64 rows.
template <int K, int N>
__global__ __launch_bounds__(256) void gemm_mfma(const float* __restrict__ A,
                                                 const bf16* __restrict__ Bh,
                                                 const bf16* __restrict__ Bl,
                                                 float* __restrict__ C,
                                                 bf16* __restrict__ Cb, int M) {
    const int lane = threadIdx.x & 63;
    const int wave = threadIdx.x >> 6;
    const int row_base = blockIdx.x * 64 + wave * 16;
    const int colt0 = blockIdx.y * 8;   // 8 col-tiles of 16
    f32x4 acc[8] = {};
    int arow = row_base + (lane & 15);
    if (arow >= M) arow = M - 1;        // clamp; stores are guarded
    const float* aptr = A + (size_t)arow * K + ((lane >> 4) * 8);
    constexpr int NT = N / 16;
    for (int kt = 0; kt < K / 32; ++kt) {
        float av[8];
        *(float4*)(av)     = *(const float4*)(aptr + kt * 32);
        *(float4*)(av + 4) = *(const float4*)(aptr + kt * 32 + 4);
        bf16x8 ah, al;
#pragma unroll
        for (int j = 0; j < 8; j++) {
            bf16 h = (bf16)av[j];
            ah[j] = h;
            al[j] = (bf16)(av[j] - (float)h);
        }
#pragma unroll
        for (int c = 0; c < 8; c++) {
            size_t fi = ((size_t)(kt * NT + colt0 + c) * 64 + lane) * 8;
            bf16x8 bh = *(const bf16x8*)(Bh + fi);
            bf16x8 bl = *(const bf16x8*)(Bl + fi);
            acc[c] = __builtin_amdgcn_mfma_f32_16x16x32_bf16(ah, bh, acc[c], 0, 0, 0);
            acc[c] = __builtin_amdgcn_mfma_f32_16x16x32_bf16(ah, bl, acc[c], 0, 0, 0);
            acc[c] = __builtin_amdgcn_mfma_f32_16x16x32_bf16(al, bh, acc[c], 0, 0, 0);
        }
    }
    const int crow0 = row_base + (lane >> 4) * 4;
    const int col = lane & 15;
#pragma unroll
    for (int c = 0; c < 8; c++)
#pragma unroll
        for (int r = 0; r < 4; r++) {
            int rr = crow0 + r;
            if (rr < M) {
                size_t o = (size_t)rr * N + (colt0 + c) * 16 + col;
                C[o] = acc[c][r];
                Cb[o] = (bf16)acc[c][r];
            }
        }
}

// ---------------- attention coefficients ----------------
__global__ void attn_coef1(const float* __restrict__ h1, const float* __restrict__ asrc,
                           const float* __restrict__ adst, float* __restrict__ as1,
                           float* __restrict__ ad1) {
    int wave = threadIdx.x >> 6, lane = threadIdx.x & 63;
    int n = blockIdx.x * 4 + wave;
    if (n >= NNODES) return;
    int h = lane >> 4;
    const float* hp = h1 + (size_t)n * F1 + lane * 8;
    float ss = 0.f, sd = 0.f;
#pragma unroll
    for (int j = 0; j < 8; j++) {
        float v = hp[j];
        int c = (lane & 15) * 8 + j;
        ss += v * asrc[h * 128 + c];
        sd += v * adst[h * 128 + c];
    }
    for (int o = 1; o < 16; o <<= 1) {
        ss += __shfl_xor(ss, o);
        sd += __shfl_xor(sd, o);
    }
    if ((lane & 15) == 0) { as1[n * 4 + h] = ss; ad1[n * 4 + h] = sd; }
}

__global__ void attn_coef2(const float* __restrict__ h2, const float* __restrict__ asrc,
                           const float* __restrict__ adst, float* __restrict__ as2,
                           float* __restrict__ ad2) {
    int wave = threadIdx.x >> 6, lane = threadIdx.x & 63;
    int n = blockIdx.x * 4 + wave;
    if (n >= NNODES) return;
    const float* hp = h2 + (size_t)n * F2 + lane * 4;
    float ss = 0.f, sd = 0.f;
#pragma unroll
    for (int j = 0; j < 4; j++) {
        float v = hp[j];
        ss += v * asrc[lane * 4 + j];
        sd += v * adst[lane * 4 + j];
    }
    for (int o = 1; o < 64; o <<= 1) {
        ss += __shfl_xor(ss, o);
        sd += __shfl_xor(sd, o);
    }
    if (lane == 0) { as2[n] = ss; ad2[n] = sd; }
}

// -------- layer 1 softmax + aggregate (alpha in LDS, bf16 gather, +bias+ELU) -----
__global__ __launch_bounds__(256) void agg1(const bf16* __restrict__ h1b,
                                            const float* __restrict__ as1,
                                            const float* __restrict__ ad1,
                                            const int* __restrict__ offs,
                                            const int* __restrict__ csr_src,
                                            const int* __restrict__ csr_eid,
                                            const float* __restrict__ b1,
                                            float* __restrict__ alpha1,
                                            float* __restrict__ h1e) {
    const int n = blockIdx.x;
    const int tid = threadIdx.x;
    const int lane = tid & 63, wave = tid >> 6;
    const int beg = offs[n];
    const int deg = offs[n + 1] - beg;

    __shared__ float wbuf[4][4];
    __shared__ float gmax[4], gden[4];
    __shared__ int   s_src[256];
    __shared__ float s_alpha[256][4];

    float4 adn4 = *(const float4*)(ad1 + n * 4);
    float adn[4] = {adn4.x, adn4.y, adn4.z, adn4.w};

    // pass 1: per-head max of leaky(e)
    float lm[4] = {-1e30f, -1e30f, -1e30f, -1e30f};
    for (int i = tid; i < deg; i += 256) {
        int s = csr_src[beg + i];
        float4 a4 = *(const float4*)(as1 + s * 4);
        float av[4] = {a4.x, a4.y, a4.z, a4.w};
#pragma unroll
        for (int h = 0; h < 4; h++) {
            float v = av[h] + adn[h];
            v = v > 0.f ? v : 0.2f * v;
            lm[h] = fmaxf(lm[h], v);
        }
    }
#pragma unroll
    for (int h = 0; h < 4; h++)
        for (int o = 1; o < 64; o <<= 1) lm[h] = fmaxf(lm[h], __shfl_xor(lm[h], o));
    if (lane == 0)
#pragma unroll
        for (int h = 0; h < 4; h++) wbuf[wave][h] = lm[h];
    __syncthreads();
    if (tid < 4)
        gmax[tid] = fmaxf(fmaxf(wbuf[0][tid], wbuf[1][tid]), fmaxf(wbuf[2][tid], wbuf[3][tid]));
    __syncthreads();
    float mx[4];
#pragma unroll
    for (int h = 0; h < 4; h++) mx[h] = gmax[h];

    // pass 2: denom
    float ls[4] = {0.f, 0.f, 0.f, 0.f};
    for (int i = tid; i < deg; i += 256) {
        int s = csr_src[beg + i];
        float4 a4 = *(const float4*)(as1 + s * 4);
        float av[4] = {a4.x, a4.y, a4.z, a4.w};
#pragma unroll
        for (int h = 0; h < 4; h++) {
            float v = av[h] + adn[h];
            v = v > 0.f ? v : 0.2f * v;
            ls[h] += __expf(v - mx[h]);
        }
    }
#pragma unroll
    for (int h = 0; h < 4; h++)
        for (int o = 1; o < 64; o <<= 1) ls[h] += __shfl_xor(ls[h], o);
    if (lane == 0)
#pragma unroll
        for (int h = 0; h < 4; h++) wbuf[wave][h] = ls[h];
    __syncthreads();
    if (tid < 4)
        gden[tid] = wbuf[0][tid] + wbuf[1][tid] + wbuf[2][tid] + wbuf[3][tid];
    __syncthreads();
    float rden[4];
#pragma unroll
    for (int h = 0; h < 4; h++) rden[h] = 1.f / gden[h];

    // tiles: stage (src, alpha[4]) in LDS once; aggregate from bf16 h rows.
    const int c2 = tid * 2;          // channels c2, c2+1 (same head)
    const int hmy = tid >> 6;        // head = c2>>7
    float acc0 = 0.f, acc1 = 0.f;
    for (int t0 = 0; t0 < deg; t0 += 256) {
        int cnt = min(256, deg - t0);
        if (tid < cnt) {
            int s = csr_src[beg + t0 + tid];
            int eid = csr_eid[beg + t0 + tid];
            s_src[tid] = s;
            float4 a4 = *(const float4*)(as1 + s * 4);
            float av[4] = {a4.x, a4.y, a4.z, a4.w};
            float al[4];
#pragma unroll
            for (int h = 0; h < 4; h++) {
                float v = av[h] + adn[h];
                v = v > 0.f ? v : 0.2f * v;
                al[h] = __expf(v - mx[h]) * rden[h];
                s_alpha[tid][h] = al[h];
            }
            *(float4*)(alpha1 + (size_t)eid * 4) = make_float4(al[0], al[1], al[2], al[3]);
        }
        __syncthreads();
        for (int i = 0; i < cnt; i++) {
            int s = s_src[i];
            float a = s_alpha[i][hmy];                      // LDS broadcast
            unsigned p = *(const unsigned*)((const char*)h1b + ((size_t)s * F1 + c2) * 2);
            acc0 += a * bflo(p);
            acc1 += a * bfhi(p);
        }
        __syncthreads();
    }
    float o0 = acc0 + b1[c2];
    float o1 = acc1 + b1[c2 + 1];
    o0 = o0 > 0.f ? o0 : expm1f(o0);   // ELU
    o1 = o1 > 0.f ? o1 : expm1f(o1);
    *(float2*)(h1e + (size_t)n * F1 + c2) = make_float2(o0, o1);
}

// -------- layer 2 softmax + aggregate (final out + alpha2) --------
__global__ __launch_bounds__(256) void agg2(const bf16* __restrict__ h2b,
                                            const float* __restrict__ as2,
                                            const float* __restrict__ ad2,
                                            const int* __restrict__ offs,
                                            const int* __restrict__ csr_src,
                                            const int* __restrict__ csr_eid,
                                            const float* __restrict__ b2,
                                            float* __restrict__ alpha2,
                                            float* __restrict__ out) {
    const int n = blockIdx.x;
    const int tid = threadIdx.x;
    const int lane = tid & 63, wave = tid >> 6;
    const int beg = offs[n];
    const int deg = offs[n + 1] - beg;

    __shared__ float wbuf[4];
    __shared__ float gm, gd;
    __shared__ int   s_src[256];
    __shared__ float s_al[256];
    __shared__ float s_part[128][2];

    float adn = ad2[n];
    float lm = -1e30f;
    for (int i = tid; i < deg; i += 256) {
        int s = csr_src[beg + i];
        float v = as2[s] + adn;
        v = v > 0.f ? v : 0.2f * v;
        lm = fmaxf(lm, v);
    }
    for (int o = 1; o < 64; o <<= 1) lm = fmaxf(lm, __shfl_xor(lm, o));
    if (lane == 0) wbuf[wave] = lm;
    __syncthreads();
    if (tid == 0) gm = fmaxf(fmaxf(wbuf[0], wbuf[1]), fmaxf(wbuf[2], wbuf[3]));
    __syncthreads();
    float mx = gm;

    float ls = 0.f;
    for (int i = tid; i < deg; i += 256) {
        int s = csr_src[beg + i];
        float v = as2[s] + adn;
        v = v > 0.f ? v : 0.2f * v;
        ls += __expf(v - mx);
    }
    for (int o = 1; o < 64; o <<= 1) ls += __shfl_xor(ls, o);
    if (lane == 0) wbuf[wave] = ls;
    __syncthreads();
    if (tid == 0) gd = wbuf[0] + wbuf[1] + wbuf[2] + wbuf[3];
    __syncthreads();
    float rden = 1.f / gd;

    // tiles: half the threads take even edges, half odd; 2 adjacent channels each
    const int half = tid >> 7;
    const int c2 = (tid & 127) * 2;
    float acc0 = 0.f, acc1 = 0.f;
    for (int t0 = 0; t0 < deg; t0 += 256) {
        int cnt = min(256, deg - t0);
        if (tid < cnt) {
            int s = csr_src[beg + t0 + tid];
            int eid = csr_eid[beg + t0 + tid];
            s_src[tid] = s;
            float v = as2[s] + adn;
            v = v > 0.f ? v : 0.2f * v;
            float a = __expf(v - mx) * rden;
            s_al[tid] = a;
            alpha2[eid] = a;
        }
        __syncthreads();
        for (int i = half; i < cnt; i += 2) {
            int s = s_src[i];
            float a = s_al[i];
            unsigned p = *(const unsigned*)((const char*)h2b + ((size_t)s * F2 + c2) * 2);
            acc0 += a * bflo(p);
            acc1 += a * bfhi(p);
        }
        __syncthreads();
    }
    if (half) { s_part[tid & 127][0] = acc0; s_part[tid & 127][1] = acc1; }
    __syncthreads();
    if (!half) {
        acc0 += s_part[tid][0];
        acc1 += s_part[tid][1];
        *(float2*)(out + (size_t)n * F2 + c2) =
            make_float2(acc0 + b2[c2], acc1 + b2[c2 + 1]);
    }
}

// ---------------- launch ----------------
extern "C" void kernel_launch(void* const* d_in, const int* in_sizes, int n_in,
                              void* d_out, int out_size, void* d_ws, size_t ws_size,
                              hipStream_t stream) {
    const float* x      = (const float*)d_in[0];
    const int*   ei     = (const int*)d_in[1];
    const float* W1     = (const float*)d_in[2];
    const float* a_src1 = (const float*)d_in[3];
    const float* a_dst1 = (const float*)d_in[4];
    const float* b1     = (const float*)d_in[5];
    const float* W2     = (const float*)d_in[6];
    const float* a_src2 = (const float*)d_in[7];
    const float* a_dst2 = (const float*)d_in[8];
    const float* b2     = (const float*)d_in[9];

    char* ws = (char*)d_ws;
    size_t off = 0;
    auto alloc = [&](size_t bytes) -> char* {
        char* p = ws + off;
        off += (bytes + 255) & ~(size_t)255;
        return p;
    };
    float* h1   = (float*)alloc((size_t)NNODES * F1 * 4);   // 41.0 MB
    bf16*  h1b  = (bf16*) alloc((size_t)NNODES * F1 * 2);   // 20.5 MB
    float* h2   = (float*)alloc((size_t)NNODES * F2 * 4);   // 20.5 MB
    bf16*  h2b  = (bf16*) alloc((size_t)NNODES * F2 * 2);   // 10.2 MB
    float* h1e  = (float*)alloc((size_t)NNODES * F1 * 4);   // 41.0 MB
    float* as1  = (float*)alloc((size_t)NNODES * 4 * 4);
    float* ad1  = (float*)alloc((size_t)NNODES * 4 * 4);
    float* as2  = (float*)alloc((size_t)NNODES * 4);
    float* ad2  = (float*)alloc((size_t)NNODES * 4);
    bf16*  W1h  = (bf16*) alloc((size_t)512 * 512 * 2);
    bf16*  W1l  = (bf16*) alloc((size_t)512 * 512 * 2);
    bf16*  W2h  = (bf16*) alloc((size_t)512 * 256 * 2);
    bf16*  W2l  = (bf16*) alloc((size_t)512 * 256 * 2);
    int*   deg  = (int*)  alloc((size_t)NNODES * 4);
    int*   offs = (int*)  alloc((size_t)(NNODES + 1) * 4);
    int*   cur  = (int*)  alloc((size_t)NNODES * 4);
    int*   csrS = (int*)  alloc((size_t)ETOT * 4);
    int*   csrE = (int*)  alloc((size_t)ETOT * 4);

    float* out2   = (float*)d_out;                      // [20000,256]
    float* alpha1 = out2 + (size_t)NNODES * F2;         // [340000,4]
    float* alpha2 = alpha1 + (size_t)ETOT * HEADS;      // [340000]

    hipMemsetAsync(deg, 0, (size_t)NNODES * 4, stream);
    deg_count<<<(ETOT + 255) / 256, 256, 0, stream>>>(ei, deg);
    scan_deg<<<1, 1024, 0, stream>>>(deg, offs, cur);
    fill_csr<<<(ETOT + 255) / 256, 256, 0, stream>>>(ei, cur, csrS, csrE);

    swizzle_w<<<(512 * 512 / 8 + 255) / 256, 256, 0, stream>>>(W1, W1h, W1l, 512, 512);
    swizzle_w<<<(512 * 256 / 8 + 255) / 256, 256, 0, stream>>>(W2, W2h, W2l, 512, 256);

    gemm_mfma<512, 512><<<dim3(313, 4), 256, 0, stream>>>(x, W1h, W1l, h1, h1b, NNODES);
    attn_coef1<<<5000, 256, 0, stream>>>(h1, a_src1, a_dst1, as1, ad1);
    agg1<<<NNODES, 256, 0, stream>>>(h1b, as1, ad1, offs, csrS, csrE, b1, alpha1, h1e);

    gemm_mfma<512, 256><<<dim3(313, 2), 256, 0, stream>>>(h1e, W2h, W2l, h2, h2b, NNODES);
    attn_coef2<<<5000, 256, 0, stream>>>(h2, a_src2, a_dst2, as2, ad2);
    agg2<<<NNODES, 256, 0, stream>>>(h2b, as2, ad2, offs, csrS, csrE, b2, alpha2, out2);
}

// Round 5
// 420.807 us; speedup vs baseline: 1.3008x; 1.0273x over previous
//
#include <hip/hip_runtime.h>
#include <hip/hip_bf16.h>
#include <cstdint>

// SimpleGAT on MI355X. Round 5:
//   R4 @432us. agg1 85us top (FETCH 156MB = 7.6x h1b table: structural 8-XCD
//   duplication for random graph; ~62us floor @2.5TB/s). Avg degree is 17,
//   so 256-thread/node blocks waste 94% of lanes in softmax passes.
// Changes:
//   1. agg1/agg2: ONE WAVE per node (block=64). Lane-parallel edges (deg<=64
//      in one chunk), regs-cached first chunk, 16B/lane dwordx4 gathers,
//      no multi-wave barriers.
//   2. attn_coef fused into GEMM epilogue (wave's 256 cols = whole heads ->
//      direct as/ad store, no atomics). h1/h2 fp32 buffers DELETED.
//   3. gemm1: 16 col-tiles/wave, grid-y 2 (A re-read 164->82 MB).
//
// MFMA 16x16x32 bf16 layouts (verified R3/R4):
//   A: lane holds A[m=lane&15][k=(lane>>4)*8 + j], j=0..7
//   B: lane holds B[k=(lane>>4)*8 + j][n=lane&15]   (pre-swizzled contiguous)
//   C/D: col = lane&15, row = (lane>>4)*4 + reg

#define NNODES 20000
#define NEDGES 320000
#define ETOT   340000   // NEDGES + NNODES self loops
#define F1     512      // HEADS*HID
#define F2     256      // OUT_CH
#define HEADS  4

typedef __bf16 bf16;
typedef __attribute__((ext_vector_type(8))) __bf16 bf16x8;
typedef __attribute__((ext_vector_type(4))) float f32x4;

__device__ __forceinline__ float bflo(unsigned p) { return __uint_as_float(p << 16); }
__device__ __forceinline__ float bfhi(unsigned p) { return __uint_as_float(p & 0xffff0000u); }

// ---------------- CSR build ----------------
__global__ void deg_count(const int* __restrict__ ei, int* __restrict__ deg) {
    int e = blockIdx.x * blockDim.x + threadIdx.x;
    if (e >= ETOT) return;
    int dst = (e < NEDGES) ? ei[NEDGES + e] : (e - NEDGES);
    atomicAdd(&deg[dst], 1);
}

// 1024 threads, 20 elems each (20480 >= 20000); one block-scan.
__global__ void scan_deg(const int* __restrict__ deg, int* __restrict__ offs,
                         int* __restrict__ cur) {
    __shared__ int sums[1024];
    const int t = threadIdx.x;
    const int PER = 20;
    int base = t * PER;
    int local[PER];
    int run = 0;
#pragma unroll
    for (int j = 0; j < PER; j++) {
        int i = base + j;
        int v = (i < NNODES) ? deg[i] : 0;
        local[j] = run;
        run += v;
    }
    sums[t] = run;
    __syncthreads();
    for (int o = 1; o < 1024; o <<= 1) {
        int v = (t >= o) ? sums[t - o] : 0;
        __syncthreads();
        sums[t] += v;
        __syncthreads();
    }
    int texcl = (t == 0) ? 0 : sums[t - 1];
#pragma unroll
    for (int j = 0; j < PER; j++) {
        int i = base + j;
        if (i < NNODES) {
            int e = texcl + local[j];
            cur[i] = e;
            offs[i] = e;
        }
    }
    if (t == 1023) offs[NNODES] = sums[1023];
}

__global__ void fill_csr(const int* __restrict__ ei, int* __restrict__ cur,
                         int* __restrict__ csr_src, int* __restrict__ csr_eid) {
    int e = blockIdx.x * blockDim.x + threadIdx.x;
    if (e >= ETOT) return;
    int src, dst;
    if (e < NEDGES) { src = ei[e]; dst = ei[NEDGES + e]; }
    else            { src = dst = e - NEDGES; }
    int p = atomicAdd(&cur[dst], 1);
    csr_src[p] = src;
    csr_eid[p] = e;
}

// ---------------- W swizzle (fp32 -> hi/lo bf16 B-fragment order) ----------------
__global__ void swizzle_w(const float* __restrict__ W, bf16* __restrict__ Wh,
                          bf16* __restrict__ Wl, int K, int N) {
    int idx = blockIdx.x * blockDim.x + threadIdx.x;  // one thread per 8 elements
    int total = (K * N) >> 3;
    if (idx >= total) return;
    int lane = idx & 63;
    int tile = idx >> 6;            // kt*(N/16) + nt
    int NT = N >> 4;
    int kt = tile / NT, nt = tile - kt * NT;
    int krow = kt * 32 + (lane >> 4) * 8;
    int col  = nt * 16 + (lane & 15);
    union { bf16 b[8]; uint4 u; } hi, lo;
#pragma unroll
    for (int j = 0; j < 8; j++) {
        float w = W[(size_t)(krow + j) * N + col];
        bf16 h = (bf16)w;
        hi.b[j] = h;
        lo.b[j] = (bf16)(w - (float)h);
    }
    *(uint4*)(Wh + (size_t)idx * 8) = hi.u;
    *(uint4*)(Wl + (size_t)idx * 8) = lo.u;
}

// ------- split-bf16 MFMA GEMM + fused attention-coefficient epilogue -------
// wave = 16 rows x 256 cols (16 col-tiles). Writes bf16 C only, plus as/ad.
// N==512: wave's 256 cols = global heads {2y, 2y+1} -> direct as1/ad1 store.
// N==256: wave's 256 cols = the single head -> direct as2/ad2 store.
template <int K, int N>
__global__ __launch_bounds__(256) void gemm_fused(const float* __restrict__ A,
                                                  const bf16* __restrict__ Bh,
                                                  const bf16* __restrict__ Bl,
                                                  bf16* __restrict__ Cb,
                                                  const float* __restrict__ asrc,
                                                  const float* __restrict__ adst,
                                                  float* __restrict__ as_out,
                                                  float* __restrict__ ad_out, int M) {
    const int lane = threadIdx.x & 63;
    const int wave = threadIdx.x >> 6;
    const int row_base = blockIdx.x * 64 + wave * 16;
    const int colt0 = blockIdx.y * 16;   // 16 col-tiles of 16
    f32x4 acc[16] = {};
    int arow = row_base + (lane & 15);
    if (arow >= M) arow = M - 1;
    const float* aptr = A + (size_t)arow * K + ((lane >> 4) * 8);
    constexpr int NT = N / 16;
    for (int kt = 0; kt < K / 32; ++kt) {
        float av[8];
        *(float4*)(av)     = *(const float4*)(aptr + kt * 32);
        *(float4*)(av + 4) = *(const float4*)(aptr + kt * 32 + 4);
        bf16x8 ah, al;
#pragma unroll
        for (int j = 0; j < 8; j++) {
            bf16 h = (bf16)av[j];
            ah[j] = h;
            al[j] = (bf16)(av[j] - (float)h);
        }
#pragma unroll
        for (int c = 0; c < 16; c++) {
            size_t fi = ((size_t)(kt * NT + colt0 + c) * 64 + lane) * 8;
            bf16x8 bh = *(const bf16x8*)(Bh + fi);
            bf16x8 bl = *(const bf16x8*)(Bl + fi);
            acc[c] = __builtin_amdgcn_mfma_f32_16x16x32_bf16(ah, bh, acc[c], 0, 0, 0);
            acc[c] = __builtin_amdgcn_mfma_f32_16x16x32_bf16(ah, bl, acc[c], 0, 0, 0);
            acc[c] = __builtin_amdgcn_mfma_f32_16x16x32_bf16(al, bh, acc[c], 0, 0, 0);
        }
    }
    const int crow0 = row_base + (lane >> 4) * 4;
    const int col15 = lane & 15;
#pragma unroll
    for (int c = 0; c < 16; c++)
#pragma unroll
        for (int r = 0; r < 4; r++) {
            int rr = crow0 + r;
            if (rr < M)
                Cb[(size_t)rr * N + (colt0 + c) * 16 + col15] = (bf16)acc[c][r];
        }

    // fused attention coefficient dots from fp32 accumulators
    if constexpr (N == 512) {
        float ss[2][4] = {}, sd[2][4] = {};
#pragma unroll
        for (int c = 0; c < 16; c++) {
            int hh = c >> 3;
            int cwh = (c & 7) * 16 + col15;
            int gh = blockIdx.y * 2 + hh;
            float was = asrc[gh * 128 + cwh];
            float wad = adst[gh * 128 + cwh];
#pragma unroll
            for (int r = 0; r < 4; r++) {
                ss[hh][r] += acc[c][r] * was;
                sd[hh][r] += acc[c][r] * wad;
            }
        }
#pragma unroll
        for (int o = 1; o < 16; o <<= 1)
#pragma unroll
            for (int hh = 0; hh < 2; hh++)
#pragma unroll
                for (int r = 0; r < 4; r++) {
                    ss[hh][r] += __shfl_xor(ss[hh][r], o);
                    sd[hh][r] += __shfl_xor(sd[hh][r], o);
                }
        if (col15 == 0) {
#pragma unroll
            for (int hh = 0; hh < 2; hh++)
#pragma unroll
                for (int r = 0; r < 4; r++) {
                    int rr = crow0 + r;
                    if (rr < M) {
                        as_out[rr * 4 + blockIdx.y * 2 + hh] = ss[hh][r];
                        ad_out[rr * 4 + blockIdx.y * 2 + hh] = sd[hh][r];
                    }
                }
        }
    } else {
        float ss[4] = {}, sd[4] = {};
#pragma unroll
        for (int c = 0; c < 16; c++) {
            int cwh = c * 16 + col15;
            float was = asrc[cwh];
            float wad = adst[cwh];
#pragma unroll
            for (int r = 0; r < 4; r++) {
                ss[r] += acc[c][r] * was;
                sd[r] += acc[c][r] * wad;
            }
        }
#pragma unroll
        for (int o = 1; o < 16; o <<= 1)
#pragma unroll
            for (int r = 0; r < 4; r++) {
                ss[r] += __shfl_xor(ss[r], o);
                sd[r] += __shfl_xor(sd[r], o);
            }
        if (col15 == 0) {
#pragma unroll
            for (int r = 0; r < 4; r++) {
                int rr = crow0 + r;
                if (rr < M) { as_out[rr] = ss[r]; ad_out[rr] = sd[r]; }
            }
        }
    }
}

// -------- layer 1 softmax + aggregate: ONE WAVE per node --------
// lane owns 8 channels (16B bf16). deg<=64 common case: single chunk in regs.
__global__ __launch_bounds__(64) void agg1(const bf16* __restrict__ h1b,
                                           const float* __restrict__ as1,
                                           const float* __restrict__ ad1,
                                           const int* __restrict__ offs,
                                           const int* __restrict__ csr_src,
                                           const int* __restrict__ csr_eid,
                                           const float* __restrict__ b1,
                                           float* __restrict__ alpha1,
                                           float* __restrict__ h1e) {
    const int n = blockIdx.x;
    const int lane = threadIdx.x;
    const int beg = offs[n];
    const int deg = offs[n + 1] - beg;

    __shared__ int   s_src[64];
    __shared__ float s_al[64][4];

    float4 ad4 = *(const float4*)(ad1 + n * 4);
    const float adn[4] = {ad4.x, ad4.y, ad4.z, ad4.w};

    // pass 1: max (cache first chunk: this lane's edge = lane)
    float v0[4];
    int s0 = 0, e0 = 0;
    float mx[4] = {-3e38f, -3e38f, -3e38f, -3e38f};
    for (int idx = lane; idx < deg; idx += 64) {
        int s = csr_src[beg + idx];
        float4 a4 = *(const float4*)(as1 + s * 4);
        float v[4] = {a4.x + adn[0], a4.y + adn[1], a4.z + adn[2], a4.w + adn[3]};
#pragma unroll
        for (int h = 0; h < 4; h++) {
            v[h] = v[h] > 0.f ? v[h] : 0.2f * v[h];
            mx[h] = fmaxf(mx[h], v[h]);
        }
        if (idx == lane) {
            s0 = s; e0 = csr_eid[beg + idx];
#pragma unroll
            for (int h = 0; h < 4; h++) v0[h] = v[h];
        }
    }
#pragma unroll
    for (int o = 1; o < 64; o <<= 1)
#pragma unroll
        for (int h = 0; h < 4; h++) mx[h] = fmaxf(mx[h], __shfl_xor(mx[h], o));

    // pass 2: denom (first chunk from regs; extras recomputed)
    float ex0[4] = {0.f, 0.f, 0.f, 0.f};
    float ls[4] = {0.f, 0.f, 0.f, 0.f};
    if (lane < deg) {
#pragma unroll
        for (int h = 0; h < 4; h++) { ex0[h] = __expf(v0[h] - mx[h]); ls[h] = ex0[h]; }
    }
    for (int idx = lane + 64; idx < deg; idx += 64) {
        int s = csr_src[beg + idx];
        float4 a4 = *(const float4*)(as1 + s * 4);
        float v[4] = {a4.x + adn[0], a4.y + adn[1], a4.z + adn[2], a4.w + adn[3]};
#pragma unroll
        for (int h = 0; h < 4; h++) {
            v[h] = v[h] > 0.f ? v[h] : 0.2f * v[h];
            ls[h] += __expf(v[h] - mx[h]);
        }
    }
#pragma unroll
    for (int o = 1; o < 64; o <<= 1)
#pragma unroll
        for (int h = 0; h < 4; h++) ls[h] += __shfl_xor(ls[h], o);
    float rden[4];
#pragma unroll
    for (int h = 0; h < 4; h++) rden[h] = 1.f / ls[h];

    // chunk loop: alpha write + LDS stash + aggregate
    float acc[8] = {};
    const int myh = lane >> 4;     // head of channels lane*8..lane*8+7
    for (int base = 0; base < deg; base += 64) {
        int idx = base + lane;
        if (idx < deg) {
            int s, e;
            float al[4];
            if (base == 0) {
                s = s0; e = e0;
#pragma unroll
                for (int h = 0; h < 4; h++) al[h] = ex0[h] * rden[h];
            } else {
                s = csr_src[beg + idx];
                e = csr_eid[beg + idx];
                float4 a4 = *(const float4*)(as1 + s * 4);
                float v[4] = {a4.x + adn[0], a4.y + adn[1], a4.z + adn[2], a4.w + adn[3]};
#pragma unroll
                for (int h = 0; h < 4; h++) {
                    v[h] = v[h] > 0.f ? v[h] : 0.2f * v[h];
                    al[h] = __expf(v[h] - mx[h]) * rden[h];
                }
            }
            s_src[lane] = s;
#pragma unroll
            for (int h = 0; h < 4; h++) s_al[lane][h] = al[h];
            *(float4*)(alpha1 + (size_t)e * 4) = make_float4(al[0], al[1], al[2], al[3]);
        }
        __syncthreads();
        int cnt = min(64, deg - base);
        for (int i = 0; i < cnt; i++) {
            int s = s_src[i];
            float a = s_al[i][myh];
            uint4 p = *(const uint4*)(h1b + (size_t)s * F1 + lane * 8);
            acc[0] += a * bflo(p.x); acc[1] += a * bfhi(p.x);
            acc[2] += a * bflo(p.y); acc[3] += a * bfhi(p.y);
            acc[4] += a * bflo(p.z); acc[5] += a * bfhi(p.z);
            acc[6] += a * bflo(p.w); acc[7] += a * bfhi(p.w);
        }
        __syncthreads();
    }
    // bias + ELU + store fp32
    const int c8 = lane * 8;
    float bv[8];
    *(float4*)(bv)     = *(const float4*)(b1 + c8);
    *(float4*)(bv + 4) = *(const float4*)(b1 + c8 + 4);
    float o[8];
#pragma unroll
    for (int j = 0; j < 8; j++) {
        float t = acc[j] + bv[j];
        o[j] = t > 0.f ? t : expm1f(t);
    }
    *(float4*)(h1e + (size_t)n * F1 + c8)     = make_float4(o[0], o[1], o[2], o[3]);
    *(float4*)(h1e + (size_t)n * F1 + c8 + 4) = make_float4(o[4], o[5], o[6], o[7]);
}

// -------- layer 2 softmax + aggregate: ONE WAVE per node --------
// lane owns 4 channels (8B bf16).
__global__ __launch_bounds__(64) void agg2(const bf16* __restrict__ h2b,
                                           const float* __restrict__ as2,
                                           const float* __restrict__ ad2,
                                           const int* __restrict__ offs,
                                           const int* __restrict__ csr_src,
                                           const int* __restrict__ csr_eid,
                                           const float* __restrict__ b2,
                                           float* __restrict__ alpha2,
                                           float* __restrict__ out) {
    const int n = blockIdx.x;
    const int lane = threadIdx.x;
    const int beg = offs[n];
    const int deg = offs[n + 1] - beg;

    __shared__ int   s_src[64];
    __shared__ float s_al[64];

    const float adn = ad2[n];

    float v0 = 0.f;
    int s0 = 0, e0 = 0;
    float mx = -3e38f;
    for (int idx = lane; idx < deg; idx += 64) {
        int s = csr_src[beg + idx];
        float v = as2[s] + adn;
        v = v > 0.f ? v : 0.2f * v;
        mx = fmaxf(mx, v);
        if (idx == lane) { s0 = s; e0 = csr_eid[beg + idx]; v0 = v; }
    }
#pragma unroll
    for (int o = 1; o < 64; o <<= 1) mx = fmaxf(mx, __shfl_xor(mx, o));

    float ex0 = 0.f, ls = 0.f;
    if (lane < deg) { ex0 = __expf(v0 - mx); ls = ex0; }
    for (int idx = lane + 64; idx < deg; idx += 64) {
        int s = csr_src[beg + idx];
        float v = as2[s] + adn;
        v = v > 0.f ? v : 0.2f * v;
        ls += __expf(v - mx);
    }
#pragma unroll
    for (int o = 1; o < 64; o <<= 1) ls += __shfl_xor(ls, o);
    float rden = 1.f / ls;

    float acc[4] = {};
    for (int base = 0; base < deg; base += 64) {
        int idx = base + lane;
        if (idx < deg) {
            int s, e;
            float a;
            if (base == 0) { s = s0; e = e0; a = ex0 * rden; }
            else {
                s = csr_src[beg + idx];
                e = csr_eid[beg + idx];
                float v = as2[s] + adn;
                v = v > 0.f ? v : 0.2f * v;
                a = __expf(v - mx) * rden;
            }
            s_src[lane] = s;
            s_al[lane] = a;
            alpha2[e] = a;
        }
        __syncthreads();
        int cnt = min(64, deg - base);
        for (int i = 0; i < cnt; i++) {
            int s = s_src[i];
            float a = s_al[i];
            uint2 p = *(const uint2*)(h2b + (size_t)s * F2 + lane * 4);
            acc[0] += a * bflo(p.x); acc[1] += a * bfhi(p.x);
            acc[2] += a * bflo(p.y); acc[3] += a * bfhi(p.y);
        }
        __syncthreads();
    }
    const int c4 = lane * 4;
    float4 bv = *(const float4*)(b2 + c4);
    *(float4*)(out + (size_t)n * F2 + c4) =
        make_float4(acc[0] + bv.x, acc[1] + bv.y, acc[2] + bv.z, acc[3] + bv.w);
}

// ---------------- launch ----------------
extern "C" void kernel_launch(void* const* d_in, const int* in_sizes, int n_in,
                              void* d_out, int out_size, void* d_ws, size_t ws_size,
                              hipStream_t stream) {
    const float* x      = (const float*)d_in[0];
    const int*   ei     = (const int*)d_in[1];
    const float* W1     = (const float*)d_in[2];
    const float* a_src1 = (const float*)d_in[3];
    const float* a_dst1 = (const float*)d_in[4];
    const float* b1     = (const float*)d_in[5];
    const float* W2     = (const float*)d_in[6];
    const float* a_src2 = (const float*)d_in[7];
    const float* a_dst2 = (const float*)d_in[8];
    const float* b2     = (const float*)d_in[9];

    char* ws = (char*)d_ws;
    size_t off = 0;
    auto alloc = [&](size_t bytes) -> char* {
        char* p = ws + off;
        off += (bytes + 255) & ~(size_t)255;
        return p;
    };
    bf16*  h1b  = (bf16*) alloc((size_t)NNODES * F1 * 2);   // 20.5 MB
    bf16*  h2b  = (bf16*) alloc((size_t)NNODES * F2 * 2);   // 10.2 MB
    float* h1e  = (float*)alloc((size_t)NNODES * F1 * 4);   // 41.0 MB
    float* as1  = (float*)alloc((size_t)NNODES * 4 * 4);
    float* ad1  = (float*)alloc((size_t)NNODES * 4 * 4);
    float* as2  = (float*)alloc((size_t)NNODES * 4);
    float* ad2  = (float*)alloc((size_t)NNODES * 4);
    bf16*  W1h  = (bf16*) alloc((size_t)512 * 512 * 2);
    bf16*  W1l  = (bf16*) alloc((size_t)512 * 512 * 2);
    bf16*  W2h  = (bf16*) alloc((size_t)512 * 256 * 2);
    bf16*  W2l  = (bf16*) alloc((size_t)512 * 256 * 2);
    int*   deg  = (int*)  alloc((size_t)NNODES * 4);
    int*   offs = (int*)  alloc((size_t)(NNODES + 1) * 4);
    int*   cur  = (int*)  alloc((size_t)NNODES * 4);
    int*   csrS = (int*)  alloc((size_t)ETOT * 4);
    int*   csrE = (int*)  alloc((size_t)ETOT * 4);

    float* out2   = (float*)d_out;                      // [20000,256]
    float* alpha1 = out2 + (size_t)NNODES * F2;         // [340000,4]
    float* alpha2 = alpha1 + (size_t)ETOT * HEADS;      // [340000]

    hipMemsetAsync(deg, 0, (size_t)NNODES * 4, stream);
    deg_count<<<(ETOT + 255) / 256, 256, 0, stream>>>(ei, deg);
    scan_deg<<<1, 1024, 0, stream>>>(deg, offs, cur);
    fill_csr<<<(ETOT + 255) / 256, 256, 0, stream>>>(ei, cur, csrS, csrE);

    swizzle_w<<<(512 * 512 / 8 + 255) / 256, 256, 0, stream>>>(W1, W1h, W1l, 512, 512);
    swizzle_w<<<(512 * 256 / 8 + 255) / 256, 256, 0, stream>>>(W2, W2h, W2l, 512, 256);

    gemm_fused<512, 512><<<dim3(313, 2), 256, 0, stream>>>(
        x, W1h, W1l, h1b, a_src1, a_dst1, as1, ad1, NNODES);
    agg1<<<NNODES, 64, 0, stream>>>(h1b, as1, ad1, offs, csrS, csrE, b1, alpha1, h1e);

    gemm_fused<512, 256><<<dim3(313, 1), 256, 0, stream>>>(
        h1e, W2h, W2l, h2b, a_src2, a_dst2, as2, ad2, NNODES);
    agg2<<<NNODES, 64, 0, stream>>>(h2b, as2, ad2, offs, csrS, csrE, b2, alpha2, out2);
}

// Round 6
// 324.849 us; speedup vs baseline: 1.6850x; 1.2954x over previous
//
#include <hip/hip_runtime.h>
#include <hip/hip_bf16.h>
#include <cstdint>

// SimpleGAT on MI355X. Round 6:
//   R5 @421us. gemm1 top @102us with MfmaUtil 12%, VALUBusy 11%, HBM 8%,
//   Occupancy 26% -> latency-bound: 2.4 waves/SIMD, no pipelining, and all
//   4 waves/block loading identical B-frags from L2.
// Changes (m97-verified structure):
//   1. B staged to LDS via global_load_lds(16B), double-buffered 2x16KB;
//      prefetch kt+1 while MFMAing kt; ds_read_b128 in the inner loop.
//   2. 8 col-tiles/wave, grid-y N/128: gemm1 1252 blocks (~4.9 waves/SIMD).
//      N=512: block cols = one head (direct as1/ad1 store).
//      N=256: half head -> atomicAdd into zeroed as2/ad2.
//
// MFMA 16x16x32 bf16 layouts (verified R3-R5):
//   A: lane holds A[m=lane&15][k=(lane>>4)*8 + j], j=0..7
//   B: lane holds B[k=(lane>>4)*8 + j][n=lane&15]   (pre-swizzled contiguous)
//   C/D: col = lane&15, row = (lane>>4)*4 + reg

#define NNODES 20000
#define NEDGES 320000
#define ETOT   340000   // NEDGES + NNODES self loops
#define F1     512      // HEADS*HID
#define F2     256      // OUT_CH
#define HEADS  4

typedef __bf16 bf16;
typedef __attribute__((ext_vector_type(8))) __bf16 bf16x8;
typedef __attribute__((ext_vector_type(4))) float f32x4;

__device__ __forceinline__ float bflo(unsigned p) { return __uint_as_float(p << 16); }
__device__ __forceinline__ float bfhi(unsigned p) { return __uint_as_float(p & 0xffff0000u); }

__device__ __forceinline__ void gload_lds16(const void* g, void* l) {
    __builtin_amdgcn_global_load_lds(
        (const __attribute__((address_space(1))) void*)g,
        (__attribute__((address_space(3))) void*)l, 16, 0, 0);
}

// ---------------- CSR build ----------------
__global__ void deg_count(const int* __restrict__ ei, int* __restrict__ deg) {
    int e = blockIdx.x * blockDim.x + threadIdx.x;
    if (e >= ETOT) return;
    int dst = (e < NEDGES) ? ei[NEDGES + e] : (e - NEDGES);
    atomicAdd(&deg[dst], 1);
}

// 1024 threads, 20 elems each (20480 >= 20000); one block-scan.
__global__ void scan_deg(const int* __restrict__ deg, int* __restrict__ offs,
                         int* __restrict__ cur) {
    __shared__ int sums[1024];
    const int t = threadIdx.x;
    const int PER = 20;
    int base = t * PER;
    int local[PER];
    int run = 0;
#pragma unroll
    for (int j = 0; j < PER; j++) {
        int i = base + j;
        int v = (i < NNODES) ? deg[i] : 0;
        local[j] = run;
        run += v;
    }
    sums[t] = run;
    __syncthreads();
    for (int o = 1; o < 1024; o <<= 1) {
        int v = (t >= o) ? sums[t - o] : 0;
        __syncthreads();
        sums[t] += v;
        __syncthreads();
    }
    int texcl = (t == 0) ? 0 : sums[t - 1];
#pragma unroll
    for (int j = 0; j < PER; j++) {
        int i = base + j;
        if (i < NNODES) {
            int e = texcl + local[j];
            cur[i] = e;
            offs[i] = e;
        }
    }
    if (t == 1023) offs[NNODES] = sums[1023];
}

__global__ void fill_csr(const int* __restrict__ ei, int* __restrict__ cur,
                         int* __restrict__ csr_src, int* __restrict__ csr_eid) {
    int e = blockIdx.x * blockDim.x + threadIdx.x;
    if (e >= ETOT) return;
    int src, dst;
    if (e < NEDGES) { src = ei[e]; dst = ei[NEDGES + e]; }
    else            { src = dst = e - NEDGES; }
    int p = atomicAdd(&cur[dst], 1);
    csr_src[p] = src;
    csr_eid[p] = e;
}

// ---------------- W swizzle (fp32 -> hi/lo bf16 B-fragment order) ----------------
__global__ void swizzle_w(const float* __restrict__ W, bf16* __restrict__ Wh,
                          bf16* __restrict__ Wl, int K, int N) {
    int idx = blockIdx.x * blockDim.x + threadIdx.x;  // one thread per 8 elements
    int total = (K * N) >> 3;
    if (idx >= total) return;
    int lane = idx & 63;
    int tile = idx >> 6;            // kt*(N/16) + nt
    int NT = N >> 4;
    int kt = tile / NT, nt = tile - kt * NT;
    int krow = kt * 32 + (lane >> 4) * 8;
    int col  = nt * 16 + (lane & 15);
    union { bf16 b[8]; uint4 u; } hi, lo;
#pragma unroll
    for (int j = 0; j < 8; j++) {
        float w = W[(size_t)(krow + j) * N + col];
        bf16 h = (bf16)w;
        hi.b[j] = h;
        lo.b[j] = (bf16)(w - (float)h);
    }
    *(uint4*)(Wh + (size_t)idx * 8) = hi.u;
    *(uint4*)(Wl + (size_t)idx * 8) = lo.u;
}

// ------- split-bf16 MFMA GEMM, LDS-staged B, fused attn-coef epilogue -------
// block = 4 waves x 16 rows = 64 rows; 8 col-tiles = 128 cols.
// LDS per kt: [hi 8KB | lo 8KB] staged by all 4 waves; double-buffered.
template <int K, int N>
__global__ __launch_bounds__(256) void gemm_fused(const float* __restrict__ A,
                                                  const bf16* __restrict__ Bh,
                                                  const bf16* __restrict__ Bl,
                                                  bf16* __restrict__ Cb,
                                                  const float* __restrict__ asrc,
                                                  const float* __restrict__ adst,
                                                  float* __restrict__ as_out,
                                                  float* __restrict__ ad_out, int M) {
    __shared__ __align__(16) char smem[2][16384];
    const int lane = threadIdx.x & 63;
    const int wave = threadIdx.x >> 6;
    const int row_base = blockIdx.x * 64 + wave * 16;
    const int colt0 = blockIdx.y * 8;   // 8 col-tiles of 16
    constexpr int NT = N / 16;

    const char* hbase = (const char*)Bh + (size_t)colt0 * 1024;
    const char* lbase = (const char*)Bl + (size_t)colt0 * 1024;
    // stage 16KB (8KB hi + 8KB lo) for K-slice kt into smem[buf]
    auto stage = [&](int kt, int buf) {
        size_t kb = (size_t)kt * NT * 1024;
#pragma unroll
        for (int q = 0; q < 4; q++) {
            int off = wave * 4096 + q * 1024;
            const char* src = (off < 8192) ? (hbase + kb + off)
                                           : (lbase + kb + (off - 8192));
            gload_lds16(src + lane * 16, &smem[buf][off]);
        }
    };

    int arow = row_base + (lane & 15);
    if (arow >= M) arow = M - 1;        // clamp; stores are guarded
    const float* aptr = A + (size_t)arow * K + ((lane >> 4) * 8);

    f32x4 acc[8] = {};
    stage(0, 0);
    __syncthreads();
    for (int kt = 0; kt < K / 32; ++kt) {
        if (kt + 1 < K / 32) stage(kt + 1, (kt + 1) & 1);
        float av[8];
        *(float4*)(av)     = *(const float4*)(aptr + kt * 32);
        *(float4*)(av + 4) = *(const float4*)(aptr + kt * 32 + 4);
        bf16x8 ah, al;
#pragma unroll
        for (int j = 0; j < 8; j++) {
            bf16 h = (bf16)av[j];
            ah[j] = h;
            al[j] = (bf16)(av[j] - (float)h);
        }
        const char* bb = smem[kt & 1];
#pragma unroll
        for (int c = 0; c < 8; c++) {
            bf16x8 bh = *(const bf16x8*)(bb + c * 1024 + lane * 16);
            bf16x8 bl = *(const bf16x8*)(bb + 8192 + c * 1024 + lane * 16);
            acc[c] = __builtin_amdgcn_mfma_f32_16x16x32_bf16(ah, bh, acc[c], 0, 0, 0);
            acc[c] = __builtin_amdgcn_mfma_f32_16x16x32_bf16(ah, bl, acc[c], 0, 0, 0);
            acc[c] = __builtin_amdgcn_mfma_f32_16x16x32_bf16(al, bh, acc[c], 0, 0, 0);
        }
        __syncthreads();
    }

    const int crow0 = row_base + (lane >> 4) * 4;
    const int col15 = lane & 15;
#pragma unroll
    for (int c = 0; c < 8; c++)
#pragma unroll
        for (int r = 0; r < 4; r++) {
            int rr = crow0 + r;
            if (rr < M)
                Cb[(size_t)rr * N + (colt0 + c) * 16 + col15] = (bf16)acc[c][r];
        }

    // fused attention coefficient dots (block's 128 cols)
    float ss[4] = {}, sd[4] = {};
#pragma unroll
    for (int c = 0; c < 8; c++) {
        int cw = blockIdx.y * 128 + c * 16 + col15;   // global column
        float was = asrc[cw];                          // asrc laid out [H*128]/[256]
        float wad = adst[cw];
#pragma unroll
        for (int r = 0; r < 4; r++) {
            ss[r] += acc[c][r] * was;
            sd[r] += acc[c][r] * wad;
        }
    }
#pragma unroll
    for (int o = 1; o < 16; o <<= 1)
#pragma unroll
        for (int r = 0; r < 4; r++) {
            ss[r] += __shfl_xor(ss[r], o);
            sd[r] += __shfl_xor(sd[r], o);
        }
    if (col15 == 0) {
        if constexpr (N == 512) {       // block cols == one head
#pragma unroll
            for (int r = 0; r < 4; r++) {
                int rr = crow0 + r;
                if (rr < M) {
                    as_out[rr * 4 + blockIdx.y] = ss[r];
                    ad_out[rr * 4 + blockIdx.y] = sd[r];
                }
            }
        } else {                         // half of the single head: reduce via atomics
#pragma unroll
            for (int r = 0; r < 4; r++) {
                int rr = crow0 + r;
                if (rr < M) {
                    atomicAdd(&as_out[rr], ss[r]);
                    atomicAdd(&ad_out[rr], sd[r]);
                }
            }
        }
    }
}

// -------- layer 1 softmax + aggregate: ONE WAVE per node --------
__global__ __launch_bounds__(64) void agg1(const bf16* __restrict__ h1b,
                                           const float* __restrict__ as1,
                                           const float* __restrict__ ad1,
                                           const int* __restrict__ offs,
                                           const int* __restrict__ csr_src,
                                           const int* __restrict__ csr_eid,
                                           const float* __restrict__ b1,
                                           float* __restrict__ alpha1,
                                           float* __restrict__ h1e) {
    const int n = blockIdx.x;
    const int lane = threadIdx.x;
    const int beg = offs[n];
    const int deg = offs[n + 1] - beg;

    __shared__ int   s_src[64];
    __shared__ float s_al[64][4];

    float4 ad4 = *(const float4*)(ad1 + n * 4);
    const float adn[4] = {ad4.x, ad4.y, ad4.z, ad4.w};

    float v0[4];
    int s0 = 0, e0 = 0;
    float mx[4] = {-3e38f, -3e38f, -3e38f, -3e38f};
    for (int idx = lane; idx < deg; idx += 64) {
        int s = csr_src[beg + idx];
        float4 a4 = *(const float4*)(as1 + s * 4);
        float v[4] = {a4.x + adn[0], a4.y + adn[1], a4.z + adn[2], a4.w + adn[3]};
#pragma unroll
        for (int h = 0; h < 4; h++) {
            v[h] = v[h] > 0.f ? v[h] : 0.2f * v[h];
            mx[h] = fmaxf(mx[h], v[h]);
        }
        if (idx == lane) {
            s0 = s; e0 = csr_eid[beg + idx];
#pragma unroll
            for (int h = 0; h < 4; h++) v0[h] = v[h];
        }
    }
#pragma unroll
    for (int o = 1; o < 64; o <<= 1)
#pragma unroll
        for (int h = 0; h < 4; h++) mx[h] = fmaxf(mx[h], __shfl_xor(mx[h], o));

    float ex0[4] = {0.f, 0.f, 0.f, 0.f};
    float ls[4] = {0.f, 0.f, 0.f, 0.f};
    if (lane < deg) {
#pragma unroll
        for (int h = 0; h < 4; h++) { ex0[h] = __expf(v0[h] - mx[h]); ls[h] = ex0[h]; }
    }
    for (int idx = lane + 64; idx < deg; idx += 64) {
        int s = csr_src[beg + idx];
        float4 a4 = *(const float4*)(as1 + s * 4);
        float v[4] = {a4.x + adn[0], a4.y + adn[1], a4.z + adn[2], a4.w + adn[3]};
#pragma unroll
        for (int h = 0; h < 4; h++) {
            v[h] = v[h] > 0.f ? v[h] : 0.2f * v[h];
            ls[h] += __expf(v[h] - mx[h]);
        }
    }
#pragma unroll
    for (int o = 1; o < 64; o <<= 1)
#pragma unroll
        for (int h = 0; h < 4; h++) ls[h] += __shfl_xor(ls[h], o);
    float rden[4];
#pragma unroll
    for (int h = 0; h < 4; h++) rden[h] = 1.f / ls[h];

    float acc[8] = {};
    const int myh = lane >> 4;
    for (int base = 0; base < deg; base += 64) {
        int idx = base + lane;
        if (idx < deg) {
            int s, e;
            float al[4];
            if (base == 0) {
                s = s0; e = e0;
#pragma unroll
                for (int h = 0; h < 4; h++) al[h] = ex0[h] * rden[h];
            } else {
                s = csr_src[beg + idx];
                e = csr_eid[beg + idx];
                float4 a4 = *(const float4*)(as1 + s * 4);
                float v[4] = {a4.x + adn[0], a4.y + adn[1], a4.z + adn[2], a4.w + adn[3]};
#pragma unroll
                for (int h = 0; h < 4; h++) {
                    v[h] = v[h] > 0.f ? v[h] : 0.2f * v[h];
                    al[h] = __expf(v[h] - mx[h]) * rden[h];
                }
            }
            s_src[lane] = s;
#pragma unroll
            for (int h = 0; h < 4; h++) s_al[lane][h] = al[h];
            *(float4*)(alpha1 + (size_t)e * 4) = make_float4(al[0], al[1], al[2], al[3]);
        }
        __syncthreads();
        int cnt = min(64, deg - base);
        for (int i = 0; i < cnt; i++) {
            int s = s_src[i];
            float a = s_al[i][myh];
            uint4 p = *(const uint4*)(h1b + (size_t)s * F1 + lane * 8);
            acc[0] += a * bflo(p.x); acc[1] += a * bfhi(p.x);
            acc[2] += a * bflo(p.y); acc[3] += a * bfhi(p.y);
            acc[4] += a * bflo(p.z); acc[5] += a * bfhi(p.z);
            acc[6] += a * bflo(p.w); acc[7] += a * bfhi(p.w);
        }
        __syncthreads();
    }
    const int c8 = lane * 8;
    float bv[8];
    *(float4*)(bv)     = *(const float4*)(b1 + c8);
    *(float4*)(bv + 4) = *(const float4*)(b1 + c8 + 4);
    float o[8];
#pragma unroll
    for (int j = 0; j < 8; j++) {
        float t = acc[j] + bv[j];
        o[j] = t > 0.f ? t : expm1f(t);
    }
    *(float4*)(h1e + (size_t)n * F1 + c8)     = make_float4(o[0], o[1], o[2], o[3]);
    *(float4*)(h1e + (size_t)n * F1 + c8 + 4) = make_float4(o[4], o[5], o[6], o[7]);
}

// -------- layer 2 softmax + aggregate: ONE WAVE per node --------
__global__ __launch_bounds__(64) void agg2(const bf16* __restrict__ h2b,
                                           const float* __restrict__ as2,
                                           const float* __restrict__ ad2,
                                           const int* __restrict__ offs,
                                           const int* __restrict__ csr_src,
                                           const int* __restrict__ csr_eid,
                                           const float* __restrict__ b2,
                                           float* __restrict__ alpha2,
                                           float* __restrict__ out) {
    const int n = blockIdx.x;
    const int lane = threadIdx.x;
    const int beg = offs[n];
    const int deg = offs[n + 1] - beg;

    __shared__ int   s_src[64];
    __shared__ float s_al[64];

    const float adn = ad2[n];

    float v0 = 0.f;
    int s0 = 0, e0 = 0;
    float mx = -3e38f;
    for (int idx = lane; idx < deg; idx += 64) {
        int s = csr_src[beg + idx];
        float v = as2[s] + adn;
        v = v > 0.f ? v : 0.2f * v;
        mx = fmaxf(mx, v);
        if (idx == lane) { s0 = s; e0 = csr_eid[beg + idx]; v0 = v; }
    }
#pragma unroll
    for (int o = 1; o < 64; o <<= 1) mx = fmaxf(mx, __shfl_xor(mx, o));

    float ex0 = 0.f, ls = 0.f;
    if (lane < deg) { ex0 = __expf(v0 - mx); ls = ex0; }
    for (int idx = lane + 64; idx < deg; idx += 64) {
        int s = csr_src[beg + idx];
        float v = as2[s] + adn;
        v = v > 0.f ? v : 0.2f * v;
        ls += __expf(v - mx);
    }
#pragma unroll
    for (int o = 1; o < 64; o <<= 1) ls += __shfl_xor(ls, o);
    float rden = 1.f / ls;

    float acc[4] = {};
    for (int base = 0; base < deg; base += 64) {
        int idx = base + lane;
        if (idx < deg) {
            int s, e;
            float a;
            if (base == 0) { s = s0; e = e0; a = ex0 * rden; }
            else {
                s = csr_src[beg + idx];
                e = csr_eid[beg + idx];
                float v = as2[s] + adn;
                v = v > 0.f ? v : 0.2f * v;
                a = __expf(v - mx) * rden;
            }
            s_src[lane] = s;
            s_al[lane] = a;
            alpha2[e] = a;
        }
        __syncthreads();
        int cnt = min(64, deg - base);
        for (int i = 0; i < cnt; i++) {
            int s = s_src[i];
            float a = s_al[i];
            uint2 p = *(const uint2*)(h2b + (size_t)s * F2 + lane * 4);
            acc[0] += a * bflo(p.x); acc[1] += a * bfhi(p.x);
            acc[2] += a * bflo(p.y); acc[3] += a * bfhi(p.y);
        }
        __syncthreads();
    }
    const int c4 = lane * 4;
    float4 bv = *(const float4*)(b2 + c4);
    *(float4*)(out + (size_t)n * F2 + c4) =
        make_float4(acc[0] + bv.x, acc[1] + bv.y, acc[2] + bv.z, acc[3] + bv.w);
}

// ---------------- launch ----------------
extern "C" void kernel_launch(void* const* d_in, const int* in_sizes, int n_in,
                              void* d_out, int out_size, void* d_ws, size_t ws_size,
                              hipStream_t stream) {
    const float* x      = (const float*)d_in[0];
    const int*   ei     = (const int*)d_in[1];
    const float* W1     = (const float*)d_in[2];
    const float* a_src1 = (const float*)d_in[3];
    const float* a_dst1 = (const float*)d_in[4];
    const float* b1     = (const float*)d_in[5];
    const float* W2     = (const float*)d_in[6];
    const float* a_src2 = (const float*)d_in[7];
    const float* a_dst2 = (const float*)d_in[8];
    const float* b2     = (const float*)d_in[9];

    char* ws = (char*)d_ws;
    size_t off = 0;
    auto alloc = [&](size_t bytes) -> char* {
        char* p = ws + off;
        off += (bytes + 255) & ~(size_t)255;
        return p;
    };
    bf16*  h1b  = (bf16*) alloc((size_t)NNODES * F1 * 2);   // 20.5 MB
    bf16*  h2b  = (bf16*) alloc((size_t)NNODES * F2 * 2);   // 10.2 MB
    float* h1e  = (float*)alloc((size_t)NNODES * F1 * 4);   // 41.0 MB
    float* as1  = (float*)alloc((size_t)NNODES * 4 * 4);
    float* ad1  = (float*)alloc((size_t)NNODES * 4 * 4);
    float* as2  = (float*)alloc((size_t)NNODES * 4);
    float* ad2  = (float*)alloc((size_t)NNODES * 4);
    bf16*  W1h  = (bf16*) alloc((size_t)512 * 512 * 2);
    bf16*  W1l  = (bf16*) alloc((size_t)512 * 512 * 2);
    bf16*  W2h  = (bf16*) alloc((size_t)512 * 256 * 2);
    bf16*  W2l  = (bf16*) alloc((size_t)512 * 256 * 2);
    int*   deg  = (int*)  alloc((size_t)NNODES * 4);
    int*   offs = (int*)  alloc((size_t)(NNODES + 1) * 4);
    int*   cur  = (int*)  alloc((size_t)NNODES * 4);
    int*   csrS = (int*)  alloc((size_t)ETOT * 4);
    int*   csrE = (int*)  alloc((size_t)ETOT * 4);

    float* out2   = (float*)d_out;                      // [20000,256]
    float* alpha1 = out2 + (size_t)NNODES * F2;         // [340000,4]
    float* alpha2 = alpha1 + (size_t)ETOT * HEADS;      // [340000]

    hipMemsetAsync(deg, 0, (size_t)NNODES * 4, stream);
    hipMemsetAsync(as2, 0, (size_t)NNODES * 4, stream);
    hipMemsetAsync(ad2, 0, (size_t)NNODES * 4, stream);
    deg_count<<<(ETOT + 255) / 256, 256, 0, stream>>>(ei, deg);
    scan_deg<<<1, 1024, 0, stream>>>(deg, offs, cur);
    fill_csr<<<(ETOT + 255) / 256, 256, 0, stream>>>(ei, cur, csrS, csrE);

    swizzle_w<<<(512 * 512 / 8 + 255) / 256, 256, 0, stream>>>(W1, W1h, W1l, 512, 512);
    swizzle_w<<<(512 * 256 / 8 + 255) / 256, 256, 0, stream>>>(W2, W2h, W2l, 512, 256);

    gemm_fused<512, 512><<<dim3(313, 4), 256, 0, stream>>>(
        x, W1h, W1l, h1b, a_src1, a_dst1, as1, ad1, NNODES);
    agg1<<<NNODES, 64, 0, stream>>>(h1b, as1, ad1, offs, csrS, csrE, b1, alpha1, h1e);

    gemm_fused<512, 256><<<dim3(313, 2), 256, 0, stream>>>(
        h1e, W2h, W2l, h2b, a_src2, a_dst2, as2, ad2, NNODES);
    agg2<<<NNODES, 64, 0, stream>>>(h2b, as2, ad2, offs, csrS, csrE, b2, alpha2, out2);
}